// Round 8
// baseline (1092.941 us; speedup 1.0000x reference)
//
#include <hip/hip_runtime.h>
#include <math.h>

// SidNet signed diffusion, S/D-decoupled + bf16 state, INTERLEAVED layout:
//   row r state = [S_r (128 bf16) | D_r (128 bf16)] = 512B.
//   S' = (Ap+Am)@S + cX  (lanes 0-31, |v|) ; D' = (Ap-Am)@D + cX (lanes 32-63, v)
// One wave per row; each edge = ONE 64-lane x 8B gather (512B) serving both
// systems. Gather loop unrolled x8 (probe: is the L2-miss path MLP-limited?).
// Edge scatter in fill2 uses nontemporal stores (probe: L2 partial-line
// writeback bounce was 76MB WRITE_SIZE @ 850 GB/s).

#define TB 256

__device__ __forceinline__ unsigned pack_bf16(float a, float b) {
    unsigned ua = __float_as_uint(a), ub = __float_as_uint(b);
    ua += 0x7fffu + ((ua >> 16) & 1u);   // RNE
    ub += 0x7fffu + ((ub >> 16) & 1u);
    return (ua >> 16) | (ub & 0xffff0000u);
}

__device__ __forceinline__ float2 unpack_bf16(unsigned w) {
    float2 r;
    r.x = __uint_as_float(w << 16);
    r.y = __uint_as_float(w & 0xffff0000u);
    return r;
}

__global__ void zero_int_kernel(int* __restrict__ p, int n) {
    int i = blockIdx.x * blockDim.x + threadIdx.x;
    if (i < n) p[i] = 0;
}

// fused histogram over both COO row lists
__global__ void hist2_kernel(const int* __restrict__ rows_p, const int* __restrict__ rows_m,
                             int E, int* __restrict__ cnt) {
    int e = blockIdx.x * blockDim.x + threadIdx.x;
    if (e < 2 * E) {
        int r = (e < E) ? rows_p[e] : rows_m[e - E];
        atomicAdd(&cnt[r], 1);
    }
}

// --- 3-phase parallel exclusive scan (safe unconditional shuffles) ---
__global__ void scanA_kernel(const int* __restrict__ cnt, int* __restrict__ bsum, int n) {
    __shared__ int wsum[16];
    int tid = threadIdx.x, lane = tid & 63, wid = tid >> 6;
    int i = blockIdx.x * 1024 + tid;
    int x = (i < n) ? cnt[i] : 0;
#pragma unroll
    for (int o = 1; o < 64; o <<= 1) { int y = __shfl_up(x, o); if (lane >= o) x += y; }
    if (lane == 63) wsum[wid] = x;
    __syncthreads();
    if (tid == 0) {
        int s = 0;
#pragma unroll
        for (int w = 0; w < 16; ++w) s += wsum[w];
        bsum[blockIdx.x] = s;
    }
}

__global__ void scanB_kernel(int* __restrict__ bsum, int nb) {
    __shared__ int wsum[16];
    int tid = threadIdx.x, lane = tid & 63, wid = tid >> 6;
    int x = (tid < nb) ? bsum[tid] : 0;
    int incl = x;
#pragma unroll
    for (int o = 1; o < 64; o <<= 1) { int y = __shfl_up(incl, o); if (lane >= o) incl += y; }
    if (lane == 63) wsum[wid] = incl;
    __syncthreads();
    if (wid == 0) {
        int s = (lane < 16) ? wsum[lane] : 0;
#pragma unroll
        for (int o = 1; o < 16; o <<= 1) { int y = __shfl_up(s, o); if (lane >= o) s += y; }
        if (lane < 16) wsum[lane] = s;
    }
    __syncthreads();
    int base = (wid > 0) ? wsum[wid - 1] : 0;
    if (tid < nb) bsum[tid] = base + incl - x;
}

__global__ void scanC_kernel(const int* __restrict__ cnt, const int* __restrict__ bsum,
                             int* __restrict__ off, int* __restrict__ cur, int n) {
    __shared__ int wsum[16];
    int tid = threadIdx.x, lane = tid & 63, wid = tid >> 6;
    int i = blockIdx.x * 1024 + tid;
    int x = (i < n) ? cnt[i] : 0;
    int incl = x;
#pragma unroll
    for (int o = 1; o < 64; o <<= 1) { int y = __shfl_up(incl, o); if (lane >= o) incl += y; }
    if (lane == 63) wsum[wid] = incl;
    __syncthreads();
    if (wid == 0) {
        int s = (lane < 16) ? wsum[lane] : 0;
#pragma unroll
        for (int o = 1; o < 16; o <<= 1) { int y = __shfl_up(s, o); if (lane >= o) s += y; }
        if (lane < 16) wsum[lane] = s;
    }
    __syncthreads();
    int base = bsum[blockIdx.x] + ((wid > 0) ? wsum[wid - 1] : 0);
    if (i < n) {
        int ex = base + incl - x;
        off[i] = ex;
        cur[i] = ex;
        if (i == n - 1) off[n] = base + incl;
    }
}

// fused fill of merged CSR: packed (col, signed val) records, nontemporal 8B
// stores (bypass L2 allocate -> no partial-line writeback bounce).
__global__ void fill2_kernel(const int* __restrict__ rows_p, const int* __restrict__ cols_p,
                             const float* __restrict__ vals_p,
                             const int* __restrict__ rows_m, const int* __restrict__ cols_m,
                             const float* __restrict__ vals_m, int E,
                             int* __restrict__ cur, int2* __restrict__ edge) {
    int e = blockIdx.x * blockDim.x + threadIdx.x;
    if (e < 2 * E) {
        int r, c; float v;
        if (e < E) { r = rows_p[e]; c = cols_p[e]; v =  vals_p[e]; }
        else       { r = rows_m[e - E]; c = cols_m[e - E]; v = -vals_m[e - E]; }
        int p = atomicAdd(&cur[r], 1);
        unsigned long long rec = (unsigned)c |
            ((unsigned long long)(unsigned)__float_as_int(v) << 32);
        __builtin_nontemporal_store(rec, (unsigned long long*)&edge[p]);
    }
}

// Interleaved init: thread i covers row r=i>>5, quad q=i&31 (features 4q..4q+3).
__global__ void init_kernel(const float* __restrict__ X, const float* __restrict__ M0,
                            uint2* __restrict__ SD, uint2* __restrict__ tXb, int n32) {
    int i = blockIdx.x * blockDim.x + threadIdx.x;
    if (i < n32) {
        int r = i >> 5, q = i & 31;
        float4 x = ((const float4*)X)[(size_t)r * 32 + q];
        float4 m = ((const float4*)M0)[(size_t)r * 32 + q];
        SD[(size_t)r * 64 + q]      = make_uint2(pack_bf16(x.x + m.x, x.y + m.y),
                                                 pack_bf16(x.z + m.z, x.w + m.w));
        SD[(size_t)r * 64 + 32 + q] = make_uint2(pack_bf16(x.x - m.x, x.y - m.y),
                                                 pack_bf16(x.z - m.z, x.w - m.w));
        tXb[(size_t)r * 32 + q]     = make_uint2(pack_bf16(0.15f * x.x, 0.15f * x.y),
                                                 pack_bf16(0.15f * x.z, 0.15f * x.w));
    }
}

// P = (S+D)/2, M = (S-D)/2 -> fp32 d_out.
__global__ void final_kernel(const uint2* __restrict__ SD,
                             float* __restrict__ P, float* __restrict__ M, int n32) {
    int i = blockIdx.x * blockDim.x + threadIdx.x;
    if (i < n32) {
        int r = i >> 5, q = i & 31;
        uint2 ws = SD[(size_t)r * 64 + q];
        uint2 wd = SD[(size_t)r * 64 + 32 + q];
        float2 s0 = unpack_bf16(ws.x), s1 = unpack_bf16(ws.y);
        float2 d0 = unpack_bf16(wd.x), d1 = unpack_bf16(wd.y);
        float4 p4 = make_float4(0.5f * (s0.x + d0.x), 0.5f * (s0.y + d0.y),
                                0.5f * (s1.x + d1.x), 0.5f * (s1.y + d1.y));
        float4 m4 = make_float4(0.5f * (s0.x - d0.x), 0.5f * (s0.y - d0.y),
                                0.5f * (s1.x - d1.x), 0.5f * (s1.y - d1.y));
        ((float4*)P)[(size_t)r * 32 + q] = p4;
        ((float4*)M)[(size_t)r * 32 + q] = m4;
    }
}

// One wave per row. lane<32: S-system (|v|); lane>=32: D-system (signed v).
// Each edge: one uint2 gather (512B across the wave) serves both systems.
// Unrolled x8: 8 gathers in flight per wave before the FMA block.
__global__ __launch_bounds__(TB) void layer_kernel(
    const int* __restrict__ off, const int2* __restrict__ edge,
    const uint2* __restrict__ In, uint2* __restrict__ Out,
    const uint2* __restrict__ tXb, int N) {
    int row = blockIdx.x * 4 + (threadIdx.x >> 6);
    if (row >= N) return;
    int lane = threadIdx.x & 63;
    int sel = lane >> 5;
    int q = lane & 31;

    uint2 t = tXb[(size_t)row * 32 + q];
    float2 t0 = unpack_bf16(t.x), t1 = unpack_bf16(t.y);
    float a0 = t0.x, a1 = t0.y, a2 = t1.x, a3 = t1.y;

    int bg = off[row], e = off[row + 1];
    int j = bg;
    for (; j + 8 <= e; j += 8) {
        int2 e0 = edge[j],     e1 = edge[j + 1], e2 = edge[j + 2], e3 = edge[j + 3];
        int2 e4 = edge[j + 4], e5 = edge[j + 5], e6 = edge[j + 6], e7 = edge[j + 7];
        uint2 w0 = In[(size_t)e0.x * 64 + lane];
        uint2 w1 = In[(size_t)e1.x * 64 + lane];
        uint2 w2 = In[(size_t)e2.x * 64 + lane];
        uint2 w3 = In[(size_t)e3.x * 64 + lane];
        uint2 w4 = In[(size_t)e4.x * 64 + lane];
        uint2 w5 = In[(size_t)e5.x * 64 + lane];
        uint2 w6 = In[(size_t)e6.x * 64 + lane];
        uint2 w7 = In[(size_t)e7.x * 64 + lane];
        float v0 = __int_as_float(e0.y), v1 = __int_as_float(e1.y);
        float v2 = __int_as_float(e2.y), v3 = __int_as_float(e3.y);
        float v4 = __int_as_float(e4.y), v5 = __int_as_float(e5.y);
        float v6 = __int_as_float(e6.y), v7 = __int_as_float(e7.y);
        if (!sel) {
            v0 = fabsf(v0); v1 = fabsf(v1); v2 = fabsf(v2); v3 = fabsf(v3);
            v4 = fabsf(v4); v5 = fabsf(v5); v6 = fabsf(v6); v7 = fabsf(v7);
        }
        float2 g0a = unpack_bf16(w0.x), g0b = unpack_bf16(w0.y);
        float2 g1a = unpack_bf16(w1.x), g1b = unpack_bf16(w1.y);
        float2 g2a = unpack_bf16(w2.x), g2b = unpack_bf16(w2.y);
        float2 g3a = unpack_bf16(w3.x), g3b = unpack_bf16(w3.y);
        float2 g4a = unpack_bf16(w4.x), g4b = unpack_bf16(w4.y);
        float2 g5a = unpack_bf16(w5.x), g5b = unpack_bf16(w5.y);
        float2 g6a = unpack_bf16(w6.x), g6b = unpack_bf16(w6.y);
        float2 g7a = unpack_bf16(w7.x), g7b = unpack_bf16(w7.y);
        a0 += v0 * g0a.x + v1 * g1a.x + v2 * g2a.x + v3 * g3a.x
            + v4 * g4a.x + v5 * g5a.x + v6 * g6a.x + v7 * g7a.x;
        a1 += v0 * g0a.y + v1 * g1a.y + v2 * g2a.y + v3 * g3a.y
            + v4 * g4a.y + v5 * g5a.y + v6 * g6a.y + v7 * g7a.y;
        a2 += v0 * g0b.x + v1 * g1b.x + v2 * g2b.x + v3 * g3b.x
            + v4 * g4b.x + v5 * g5b.x + v6 * g6b.x + v7 * g7b.x;
        a3 += v0 * g0b.y + v1 * g1b.y + v2 * g2b.y + v3 * g3b.y
            + v4 * g4b.y + v5 * g5b.y + v6 * g6b.y + v7 * g7b.y;
    }
    for (; j < e; ++j) {
        int2 ed = edge[j];
        uint2 w = In[(size_t)ed.x * 64 + lane];
        float v = __int_as_float(ed.y);
        if (!sel) v = fabsf(v);
        float2 ga = unpack_bf16(w.x), gb = unpack_bf16(w.y);
        a0 += v * ga.x; a1 += v * ga.y; a2 += v * gb.x; a3 += v * gb.y;
    }
    Out[(size_t)row * 64 + lane] = make_uint2(pack_bf16(a0, a1), pack_bf16(a2, a3));
}

extern "C" void kernel_launch(void* const* d_in, const int* in_sizes, int n_in,
                              void* d_out, int out_size, void* d_ws, size_t ws_size,
                              hipStream_t stream) {
    const int*   rows_p = (const int*)d_in[0];
    const int*   cols_p = (const int*)d_in[1];
    const float* vals_p = (const float*)d_in[2];
    const int*   rows_m = (const int*)d_in[3];
    const int*   cols_m = (const int*)d_in[4];
    const float* vals_m = (const float*)d_in[5];
    const float* X      = (const float*)d_in[6];
    const float* M0     = (const float*)d_in[7];

    const int E = in_sizes[0];
    const int D = 128;
    const int N = in_sizes[6] / D;
    const int K = 10;
    const int E2 = 2 * E;
    const size_t ND = (size_t)N * D;
    const int N32 = N * 32;

    float* outP = (float*)d_out;
    float* outM = outP + ND;

    char* ws = (char*)d_ws;
    size_t o = 0;
    auto alloc = [&](size_t b) -> void* {
        void* p = ws + o;
        o += (b + 255) & ~(size_t)255;
        return p;
    };
    uint2* SDA  = (uint2*)alloc((size_t)N * 64 * 8);
    uint2* SDB  = (uint2*)alloc((size_t)N * 64 * 8);
    uint2* tXb  = (uint2*)alloc((size_t)N * 32 * 8);
    int*   cnt  = (int*)alloc((size_t)N * sizeof(int));
    int*   off  = (int*)alloc((size_t)(N + 1) * sizeof(int));
    int*   cur  = (int*)alloc((size_t)N * sizeof(int));
    int*   bsum = (int*)alloc(1024 * sizeof(int));
    int2*  edge = (int2*)alloc((size_t)E2 * sizeof(int2));

    int gN   = (N + TB - 1) / TB;
    int gE2  = (E2 + TB - 1) / TB;
    int gN32 = (N32 + TB - 1) / TB;
    int nb   = (N + 1023) / 1024;

    // --- build merged CSR ---
    zero_int_kernel<<<gN, TB, 0, stream>>>(cnt, N);
    hist2_kernel<<<gE2, TB, 0, stream>>>(rows_p, rows_m, E, cnt);
    scanA_kernel<<<nb, 1024, 0, stream>>>(cnt, bsum, N);
    scanB_kernel<<<1, 1024, 0, stream>>>(bsum, nb);
    scanC_kernel<<<nb, 1024, 0, stream>>>(cnt, bsum, off, cur, N);
    fill2_kernel<<<gE2, TB, 0, stream>>>(rows_p, cols_p, vals_p,
                                         rows_m, cols_m, vals_m, E, cur, edge);

    // --- init interleaved bf16 state ---
    init_kernel<<<gN32, TB, 0, stream>>>(X, M0, SDA, tXb, N32);

    // --- K layers, ping-pong; K even -> final state lands in SDA ---
    int gL = (N + 3) / 4;
    uint2 *Si = SDA, *So = SDB;
    for (int k = 0; k < K; ++k) {
        layer_kernel<<<gL, TB, 0, stream>>>(off, edge, Si, So, tXb, N);
        uint2* t = Si; Si = So; So = t;
    }

    // --- unpack to fp32 outputs ---
    final_kernel<<<gN32, TB, 0, stream>>>(Si, outP, outM, N32);
}

// Round 9
// 1006.320 us; speedup vs baseline: 1.0861x; 1.0861x over previous
//
#include <hip/hip_runtime.h>
#include <math.h>

// SidNet signed diffusion, S/D-decoupled + bf16 interleaved state (round 7/8
// proven layer). New: CSR build via LDS write-combined bucket partition
// (128 buckets of 512 rows) -> kills the 8x partial-sector writeback bounce
// of the random 8B edge scatter (fill2 was 92us, WRITE_SIZE 79MB for 9.6MB).
// Final unpack fused into layer 10 (shfl_xor(32) pairs S/D halves).

#define TB 256

__device__ __forceinline__ unsigned pack_bf16(float a, float b) {
    unsigned ua = __float_as_uint(a), ub = __float_as_uint(b);
    ua += 0x7fffu + ((ua >> 16) & 1u);   // RNE
    ub += 0x7fffu + ((ub >> 16) & 1u);
    return (ua >> 16) | (ub & 0xffff0000u);
}

__device__ __forceinline__ float2 unpack_bf16(unsigned w) {
    float2 r;
    r.x = __uint_as_float(w << 16);
    r.y = __uint_as_float(w & 0xffff0000u);
    return r;
}

__global__ void zero_int_kernel(int* __restrict__ p, int n) {
    int i = blockIdx.x * blockDim.x + threadIdx.x;
    if (i < n) p[i] = 0;
}

// K1: bucket histogram (bucket = row>>9), LDS-staged to keep global atomics rare.
__global__ void bucket_count_kernel(const int* __restrict__ rows_p,
                                    const int* __restrict__ rows_m,
                                    int E, int* __restrict__ bcnt) {
    __shared__ int h[128];
    for (int i = threadIdx.x; i < 128; i += TB) h[i] = 0;
    __syncthreads();
    int total = 2 * E;
    for (int e = blockIdx.x * TB + threadIdx.x; e < total; e += gridDim.x * TB) {
        int r = (e < E) ? rows_p[e] : rows_m[e - E];
        atomicAdd(&h[r >> 9], 1);
    }
    __syncthreads();
    for (int i = threadIdx.x; i < 128; i += TB)
        if (h[i]) atomicAdd(&bcnt[i], h[i]);
}

// K2: single-wave exclusive scan of 128 bucket counts -> boff[0..128], bcur copy.
__global__ void bucket_scan_kernel(const int* __restrict__ bcnt,
                                   int* __restrict__ boff, int* __restrict__ bcur) {
    int l = threadIdx.x;              // 0..63
    int v0 = bcnt[l], v1 = bcnt[l + 64];
    int i0 = v0, i1 = v1;
#pragma unroll
    for (int o = 1; o < 64; o <<= 1) { int y = __shfl_up(i0, o); if (l >= o) i0 += y; }
#pragma unroll
    for (int o = 1; o < 64; o <<= 1) { int y = __shfl_up(i1, o); if (l >= o) i1 += y; }
    int t0 = __shfl(i0, 63);          // total of low half
    int e0 = i0 - v0;
    int e1 = i1 - v1 + t0;
    boff[l] = e0;      boff[l + 64] = e1;
    bcur[l] = e0;      bcur[l + 64] = e1;
    if (l == 63) boff[128] = i1 + t0; // grand total = 2E
}

// K3: tile-local bucket sort in LDS, then coalesced run-writes to stage[].
// Record: key = (r<<16)|c (r,c < 65536), val bits separate. bucket = key>>25.
__global__ __launch_bounds__(TB) void partition_kernel(
    const int* __restrict__ rows_p, const int* __restrict__ cols_p,
    const float* __restrict__ vals_p,
    const int* __restrict__ rows_m, const int* __restrict__ cols_m,
    const float* __restrict__ vals_m, int E,
    int* __restrict__ bcur_g, uint2* __restrict__ stage) {
    __shared__ unsigned keys[2048];
    __shared__ float    vals[2048];
    __shared__ unsigned skeys[2048];
    __shared__ float    svals[2048];
    __shared__ int h[128], boff[128], bcur[128], bbase[128];
    int tile0 = blockIdx.x * 2048;
    int cnt = min(2048, 2 * E - tile0);

    for (int i = threadIdx.x; i < cnt; i += TB) {
        int e = tile0 + i; int r, c; float v;
        if (e < E) { r = rows_p[e]; c = cols_p[e]; v = vals_p[e]; }
        else       { r = rows_m[e - E]; c = cols_m[e - E]; v = -vals_m[e - E]; }
        keys[i] = ((unsigned)r << 16) | (unsigned)c;
        vals[i] = v;
    }
    for (int i = threadIdx.x; i < 128; i += TB) { h[i] = 0; bcur[i] = 0; }
    __syncthreads();
    for (int i = threadIdx.x; i < cnt; i += TB) atomicAdd(&h[keys[i] >> 25], 1);
    __syncthreads();
    if (threadIdx.x < 64) {           // wave 0: scan 128 counters
        int l = threadIdx.x;
        int v0 = h[l], v1 = h[l + 64], i0 = v0, i1 = v1;
#pragma unroll
        for (int o = 1; o < 64; o <<= 1) { int y = __shfl_up(i0, o); if (l >= o) i0 += y; }
#pragma unroll
        for (int o = 1; o < 64; o <<= 1) { int y = __shfl_up(i1, o); if (l >= o) i1 += y; }
        int t0 = __shfl(i0, 63);
        boff[l] = i0 - v0;
        boff[l + 64] = i1 - v1 + t0;
    }
    __syncthreads();
    for (int i = threadIdx.x; i < cnt; i += TB) {
        unsigned k = keys[i]; int b = k >> 25;
        int p = boff[b] + atomicAdd(&bcur[b], 1);
        skeys[p] = k; svals[p] = vals[i];
    }
    __syncthreads();
    if (threadIdx.x < 128) {
        int c_ = h[threadIdx.x];
        if (c_) bbase[threadIdx.x] = atomicAdd(&bcur_g[threadIdx.x], c_);
    }
    __syncthreads();
    // bucket-sorted LDS -> stage: consecutive i in a bucket run -> consecutive
    // global addresses; each sector is filled by one block in one burst.
    for (int i = threadIdx.x; i < cnt; i += TB) {
        unsigned k = skeys[i]; int b = k >> 25;
        stage[bbase[b] + (i - boff[b])] = make_uint2(k, __float_as_uint(svals[i]));
    }
}

// K4: one block per bucket (512 rows). LDS row-histogram + scan -> off[],
// then scatter records into the bucket's contiguous CSR range (block-owned).
__global__ __launch_bounds__(TB) void csr_finalize_kernel(
    const uint2* __restrict__ stage, const int* __restrict__ boff_g,
    int NBv, int N, int E2, int* __restrict__ off, int2* __restrict__ edge) {
    __shared__ int rc[512], ro[512], rcur[512];
    int b = blockIdx.x;
    int row0 = b << 9;
    int s0 = boff_g[b], s1 = boff_g[b + 1];
    for (int i = threadIdx.x; i < 512; i += TB) { rc[i] = 0; rcur[i] = 0; }
    __syncthreads();
    for (int i = s0 + threadIdx.x; i < s1; i += TB)
        atomicAdd(&rc[(stage[i].x >> 16) - row0], 1);
    __syncthreads();
    if (threadIdx.x < 64) {           // wave 0: exclusive scan of 512 counts
        int l = threadIdx.x;
        int s = 0, loc[8];
#pragma unroll
        for (int j = 0; j < 8; ++j) { loc[j] = s; s += rc[l * 8 + j]; }
        int incl = s;
#pragma unroll
        for (int o = 1; o < 64; o <<= 1) { int y = __shfl_up(incl, o); if (l >= o) incl += y; }
        int base = incl - s;
#pragma unroll
        for (int j = 0; j < 8; ++j) ro[l * 8 + j] = base + loc[j];
    }
    __syncthreads();
    for (int i = threadIdx.x; i < 512; i += TB) {
        int r = row0 + i;
        if (r < N) off[r] = s0 + ro[i];
    }
    if (b == NBv - 1 && threadIdx.x == 0) off[N] = E2;
    for (int i = s0 + threadIdx.x; i < s1; i += TB) {
        uint2 rec = stage[i];
        int lr = (int)(rec.x >> 16) - row0;
        int p = s0 + ro[lr] + atomicAdd(&rcur[lr], 1);
        edge[p] = make_int2((int)(rec.x & 0xffffu), (int)rec.y);
    }
}

// Interleaved init: thread i covers row r=i>>5, quad q=i&31 (features 4q..4q+3).
__global__ void init_kernel(const float* __restrict__ X, const float* __restrict__ M0,
                            uint2* __restrict__ SD, uint2* __restrict__ tXb, int n32) {
    int i = blockIdx.x * blockDim.x + threadIdx.x;
    if (i < n32) {
        int r = i >> 5, q = i & 31;
        float4 x = ((const float4*)X)[(size_t)r * 32 + q];
        float4 m = ((const float4*)M0)[(size_t)r * 32 + q];
        SD[(size_t)r * 64 + q]      = make_uint2(pack_bf16(x.x + m.x, x.y + m.y),
                                                 pack_bf16(x.z + m.z, x.w + m.w));
        SD[(size_t)r * 64 + 32 + q] = make_uint2(pack_bf16(x.x - m.x, x.y - m.y),
                                                 pack_bf16(x.z - m.z, x.w - m.w));
        tXb[(size_t)r * 32 + q]     = make_uint2(pack_bf16(0.15f * x.x, 0.15f * x.y),
                                                 pack_bf16(0.15f * x.z, 0.15f * x.w));
    }
}

// One wave per row. lane<32: S-system (|v|); lane>=32: D-system (signed v).
// Each edge: one uint2 gather (512B across the wave) serves both systems.
// last!=0: fused final -> shfl_xor(32) pairs S/D halves, write fp32 P/M.
__global__ __launch_bounds__(TB) void layer_kernel(
    const int* __restrict__ off, const int2* __restrict__ edge,
    const uint2* __restrict__ In, uint2* __restrict__ Out,
    const uint2* __restrict__ tXb,
    float* __restrict__ Pout, float* __restrict__ Mout, int last, int N) {
    int row = blockIdx.x * 4 + (threadIdx.x >> 6);
    if (row >= N) return;
    int lane = threadIdx.x & 63;
    int sel = lane >> 5;
    int q = lane & 31;

    uint2 t = tXb[(size_t)row * 32 + q];
    float2 t0 = unpack_bf16(t.x), t1 = unpack_bf16(t.y);
    float a0 = t0.x, a1 = t0.y, a2 = t1.x, a3 = t1.y;

    int bg = off[row], e = off[row + 1];
    int j = bg;
    for (; j + 8 <= e; j += 8) {
        int2 e0 = edge[j],     e1 = edge[j + 1], e2 = edge[j + 2], e3 = edge[j + 3];
        int2 e4 = edge[j + 4], e5 = edge[j + 5], e6 = edge[j + 6], e7 = edge[j + 7];
        uint2 w0 = In[(size_t)e0.x * 64 + lane];
        uint2 w1 = In[(size_t)e1.x * 64 + lane];
        uint2 w2 = In[(size_t)e2.x * 64 + lane];
        uint2 w3 = In[(size_t)e3.x * 64 + lane];
        uint2 w4 = In[(size_t)e4.x * 64 + lane];
        uint2 w5 = In[(size_t)e5.x * 64 + lane];
        uint2 w6 = In[(size_t)e6.x * 64 + lane];
        uint2 w7 = In[(size_t)e7.x * 64 + lane];
        float v0 = __int_as_float(e0.y), v1 = __int_as_float(e1.y);
        float v2 = __int_as_float(e2.y), v3 = __int_as_float(e3.y);
        float v4 = __int_as_float(e4.y), v5 = __int_as_float(e5.y);
        float v6 = __int_as_float(e6.y), v7 = __int_as_float(e7.y);
        if (!sel) {
            v0 = fabsf(v0); v1 = fabsf(v1); v2 = fabsf(v2); v3 = fabsf(v3);
            v4 = fabsf(v4); v5 = fabsf(v5); v6 = fabsf(v6); v7 = fabsf(v7);
        }
        float2 g0a = unpack_bf16(w0.x), g0b = unpack_bf16(w0.y);
        float2 g1a = unpack_bf16(w1.x), g1b = unpack_bf16(w1.y);
        float2 g2a = unpack_bf16(w2.x), g2b = unpack_bf16(w2.y);
        float2 g3a = unpack_bf16(w3.x), g3b = unpack_bf16(w3.y);
        float2 g4a = unpack_bf16(w4.x), g4b = unpack_bf16(w4.y);
        float2 g5a = unpack_bf16(w5.x), g5b = unpack_bf16(w5.y);
        float2 g6a = unpack_bf16(w6.x), g6b = unpack_bf16(w6.y);
        float2 g7a = unpack_bf16(w7.x), g7b = unpack_bf16(w7.y);
        a0 += v0 * g0a.x + v1 * g1a.x + v2 * g2a.x + v3 * g3a.x
            + v4 * g4a.x + v5 * g5a.x + v6 * g6a.x + v7 * g7a.x;
        a1 += v0 * g0a.y + v1 * g1a.y + v2 * g2a.y + v3 * g3a.y
            + v4 * g4a.y + v5 * g5a.y + v6 * g6a.y + v7 * g7a.y;
        a2 += v0 * g0b.x + v1 * g1b.x + v2 * g2b.x + v3 * g3b.x
            + v4 * g4b.x + v5 * g5b.x + v6 * g6b.x + v7 * g7b.x;
        a3 += v0 * g0b.y + v1 * g1b.y + v2 * g2b.y + v3 * g3b.y
            + v4 * g4b.y + v5 * g5b.y + v6 * g6b.y + v7 * g7b.y;
    }
    for (; j < e; ++j) {
        int2 ed = edge[j];
        uint2 w = In[(size_t)ed.x * 64 + lane];
        float v = __int_as_float(ed.y);
        if (!sel) v = fabsf(v);
        float2 ga = unpack_bf16(w.x), gb = unpack_bf16(w.y);
        a0 += v * ga.x; a1 += v * ga.y; a2 += v * gb.x; a3 += v * gb.y;
    }

    if (!last) {
        Out[(size_t)row * 64 + lane] = make_uint2(pack_bf16(a0, a1), pack_bf16(a2, a3));
    } else {
        // pair with the other half: lane<32 holds S, lane>=32 holds D (same q)
        float b0 = __shfl_xor(a0, 32), b1 = __shfl_xor(a1, 32);
        float b2 = __shfl_xor(a2, 32), b3 = __shfl_xor(a3, 32);
        if (sel == 0) {   // P = (S+D)/2
            ((float4*)Pout)[(size_t)row * 32 + q] =
                make_float4(0.5f * (a0 + b0), 0.5f * (a1 + b1),
                            0.5f * (a2 + b2), 0.5f * (a3 + b3));
        } else {          // M = (S-D)/2, here a=D, b=S
            ((float4*)Mout)[(size_t)row * 32 + q] =
                make_float4(0.5f * (b0 - a0), 0.5f * (b1 - a1),
                            0.5f * (b2 - a2), 0.5f * (b3 - a3));
        }
    }
}

extern "C" void kernel_launch(void* const* d_in, const int* in_sizes, int n_in,
                              void* d_out, int out_size, void* d_ws, size_t ws_size,
                              hipStream_t stream) {
    const int*   rows_p = (const int*)d_in[0];
    const int*   cols_p = (const int*)d_in[1];
    const float* vals_p = (const float*)d_in[2];
    const int*   rows_m = (const int*)d_in[3];
    const int*   cols_m = (const int*)d_in[4];
    const float* vals_m = (const float*)d_in[5];
    const float* X      = (const float*)d_in[6];
    const float* M0     = (const float*)d_in[7];

    const int E = in_sizes[0];
    const int D = 128;
    const int N = in_sizes[6] / D;       // 50000 (<65536: 16-bit r/c packing ok)
    const int K = 10;
    const int E2 = 2 * E;
    const size_t ND = (size_t)N * D;
    const int N32 = N * 32;
    const int NBv = (N + 511) >> 9;      // buckets of 512 rows, <=128

    float* outP = (float*)d_out;
    float* outM = outP + ND;

    char* ws = (char*)d_ws;
    size_t o = 0;
    auto alloc = [&](size_t b) -> void* {
        void* p = ws + o;
        o += (b + 255) & ~(size_t)255;
        return p;
    };
    uint2* SDA  = (uint2*)alloc((size_t)N * 64 * 8);
    uint2* SDB  = (uint2*)alloc((size_t)N * 64 * 8);
    uint2* tXb  = (uint2*)alloc((size_t)N * 32 * 8);
    int*   off  = (int*)alloc((size_t)(N + 1) * sizeof(int));
    int2*  edge = (int2*)alloc((size_t)E2 * sizeof(int2));
    int*   bcnt = (int*)alloc(128 * sizeof(int));
    int*   boff = (int*)alloc(129 * sizeof(int));
    int*   bcur = (int*)alloc(128 * sizeof(int));
    // stage aliases SDB: consumed by csr_finalize before layer 0 writes SDB.
    uint2* stage = SDB;

    int gN32 = (N32 + TB - 1) / TB;
    int gTiles = (E2 + 2047) / 2048;

    // --- CSR build: bucket partition with LDS write-combining ---
    zero_int_kernel<<<1, 128, 0, stream>>>(bcnt, 128);
    bucket_count_kernel<<<512, TB, 0, stream>>>(rows_p, rows_m, E, bcnt);
    bucket_scan_kernel<<<1, 64, 0, stream>>>(bcnt, boff, bcur);
    partition_kernel<<<gTiles, TB, 0, stream>>>(rows_p, cols_p, vals_p,
                                                rows_m, cols_m, vals_m, E,
                                                bcur, stage);
    csr_finalize_kernel<<<NBv, TB, 0, stream>>>(stage, boff, NBv, N, E2, off, edge);

    // --- init interleaved bf16 state ---
    init_kernel<<<gN32, TB, 0, stream>>>(X, M0, SDA, tXb, N32);

    // --- K layers, ping-pong; last layer writes fp32 P/M directly ---
    int gL = (N + 3) / 4;
    uint2 *Si = SDA, *So = SDB;
    for (int k = 0; k < K; ++k) {
        int last = (k == K - 1);
        layer_kernel<<<gL, TB, 0, stream>>>(off, edge, Si, So, tXb,
                                            outP, outM, last, N);
        uint2* t = Si; Si = So; So = t;
    }
}